// Round 11
// baseline (87.078 us; speedup 1.0000x reference)
//
#include <hip/hip_runtime.h>
#include <hip/hip_bf16.h>
#include <cstdint>
#include <cstddef>

#define BB 32
#define SS 4096
#define DD 256
#define UU 256
#define BM 32
#define NCH (SS / BM)   // 128 chunks per batch

typedef __attribute__((ext_vector_type(8))) short short8;
typedef __attribute__((ext_vector_type(4))) float f32x4;

__device__ __forceinline__ unsigned short f2bf(float x) {
  union { float f; unsigned int u; } c; c.f = x;
  unsigned int r = c.u + 0x7FFFu + ((c.u >> 16) & 1u);
  return (unsigned short)(r >> 16);
}

__device__ __forceinline__ unsigned int bfpack2(float lo, float hi) {
  union { float f; unsigned int u; } a, b;
  a.f = hi; b.f = lo;
  return __builtin_amdgcn_perm(a.u + 0x8000u, b.u + 0x8000u, 0x07060302u);
}

__device__ __forceinline__ short8 bfpack8(float4 f0, float4 f1) {
  union { unsigned int u[4]; short8 s; } r;
  r.u[0] = bfpack2(f0.x, f0.y);
  r.u[1] = bfpack2(f0.z, f0.w);
  r.u[2] = bfpack2(f1.x, f1.y);
  r.u[3] = bfpack2(f1.z, f1.w);
  return r.s;
}

// DPP row-rotate add: reduce within a 16-lane row at VALU rate
template <int CTRL>
__device__ __forceinline__ float dppadd(float x) {
  union { float f; int i; } a, b;
  a.f = x;
  b.i = __builtin_amdgcn_update_dpp(0, a.i, CTRL, 0xF, 0xF, true);
  return x + b.f;
}
__device__ __forceinline__ float row16_sum(float x) {
  x = dppadd<0x128>(x);   // row_ror:8
  x = dppadd<0x124>(x);   // row_ror:4
  x = dppadd<0x122>(x);   // row_ror:2
  x = dppadd<0x121>(x);   // row_ror:1
  return x;
}

// K1: posb[b][u] = position[b] @ W1[:,u] + b1[u] + b2[u]   (exact fp32)
__global__ void k_posproj(const float* __restrict__ pos, const float* __restrict__ W1,
                          const float* __restrict__ b1, const float* __restrict__ b2,
                          float* __restrict__ posb) {
  __shared__ float p[DD];
  int b = blockIdx.x, u = threadIdx.x;
  p[u] = pos[b * DD + u];
  __syncthreads();
  float acc = b1[u] + b2[u];
#pragma unroll 4
  for (int d = 0; d < DD; ++d) acc = fmaf(p[d], W1[(size_t)d * UU + u], acc);
  posb[b * UU + u] = acc;
}

// K1b: w2t[u][d] = bf16(W2[d][u])  (tiled transpose)
__global__ void k_w2t(const float* __restrict__ W2, unsigned short* __restrict__ w2t) {
  __shared__ unsigned short tile[16][17];
  int di = blockIdx.x * 16, ui = blockIdx.y * 16;
  int t = threadIdx.x;
  int r = t >> 4, c = t & 15;
  tile[c][r] = f2bf(W2[(size_t)(di + r) * UU + ui + c]);
  __syncthreads();
  w2t[(size_t)(ui + r) * DD + di + c] = tile[r][c];
}

// K2: thin-block streamed kernel. BM=32 rows, 256 threads (4 waves, wave=64-u quarter).
// LDS: B dbuf 2x16KB @0 ; A k-slice dbuf 2x4KB @32768. Total 40960 -> 4 blocks/CU.
// A streamed in 4 slices of 64k through the K-loop (fp32 load even t, pack odd t).
__global__ __launch_bounds__(256, 4) void k_score_ctx(
    const float* __restrict__ options, const unsigned short* __restrict__ w2t,
    const float* __restrict__ posb, const float* __restrict__ V,
    const float* __restrict__ bvp, float* __restrict__ scores,
    float* __restrict__ part) {
  __shared__ __align__(16) unsigned char smem[40960];
  unsigned char* const aLDS = smem + 32768;

  const int tid = threadIdx.x;
  const int ch = blockIdx.x;            // 0..127
  const int b  = blockIdx.y;
  const int s0 = ch * BM;
  const int wid = tid >> 6;             // u-quarter
  const int l = tid & 63;
  const int il = l & 15, kg = l >> 4;

  const float* optb = options + ((size_t)b * SS + s0) * DD;

  // ---- A staging geometry: thread stages row=tid>>3, octet=tid&7 ----
  const int arow = tid >> 3, aoct = tid & 7;
  const float* paBase = optb + (size_t)arow * DD + aoct * 8;
  const int awoff = arow * 128 + ((aoct ^ (arow & 7)) << 4);

  // ---- B gll geometry: call i covers phys 16B-slots p = i*256+tid ----
  const unsigned short* srcB[4];
#pragma unroll
  for (int i = 0; i < 4; ++i) {
    int p = i * 256 + tid;
    int u = p >> 2;
    int oct = (p & 3) ^ ((u >> 1) & 3);
    srcB[i] = w2t + (size_t)u * DD + oct * 8;
  }

#define GLLB(T, SLOT)                                                           \
  {                                                                             \
    _Pragma("unroll")                                                           \
    for (int i = 0; i < 4; ++i)                                                 \
      __builtin_amdgcn_global_load_lds(                                         \
          (const __attribute__((address_space(1))) void*)(srcB[i] + (T) * 32),  \
          (__attribute__((address_space(3))) void*)(smem + (SLOT) * 16384 +     \
                                                   i * 4096 + wid * 1024),      \
          16, 0, 0);                                                            \
  }

  // ---- MFMA read offsets ----
  int aoff[2][2];
#pragma unroll
  for (int mi = 0; mi < 2; ++mi)
#pragma unroll
    for (int kc = 0; kc < 2; ++kc)
      aoff[mi][kc] = (mi * 16 + il) * 128 + ((((kc * 4) + kg) ^ (il & 7)) << 4);
  int boffs[4];
#pragma unroll
  for (int ni = 0; ni < 4; ++ni) {
    int u = wid * 64 + ni * 16 + il;
    boffs[ni] = u * 64 + ((kg ^ ((u >> 1) & 3)) << 4);
  }

  f32x4 acc[2][4];
#pragma unroll
  for (int mi = 0; mi < 2; ++mi)
#pragma unroll
    for (int ni = 0; ni < 4; ++ni) {
      f32x4 z = {0.f, 0.f, 0.f, 0.f};
      acc[mi][ni] = z;
    }

  float4 aR0, aR1;

  // ---- prologue: A slice0 staged; gll B tile0; A slice1 loads in flight ----
  {
    float4 a00 = *(const float4*)(paBase);
    float4 a01 = *(const float4*)(paBase + 4);
    GLLB(0, 0);
    aR0 = *(const float4*)(paBase + 64);
    aR1 = *(const float4*)(paBase + 68);
    *(short8*)(aLDS + awoff) = bfpack8(a00, a01);   // compiler waits a00/a01
    asm volatile("s_waitcnt vmcnt(2) lgkmcnt(0)" ::: "memory"); // tile0 done, aR in flight
    __builtin_amdgcn_sched_barrier(0);
    __builtin_amdgcn_s_barrier();
  }

  // ---- K-loop: 8 iters of BK=32. A slices: t/2; pack slice s+1 at odd t. ----
#pragma unroll
  for (int t = 0; t < 8; ++t) {
    const int cur = t & 1;
    if ((t & 1) && t < 7) {
      const int ns = (t + 1) >> 1;                   // 1,2,3
      *(short8*)(aLDS + (ns & 1) * 4096 + awoff) = bfpack8(aR0, aR1);
    }
    if (t < 7) GLLB(t + 1, (t + 1) & 1);
    if (t == 2 || t == 4) {
      const int ls = (t >> 1) + 1;                   // 2,3
      aR0 = *(const float4*)(paBase + ls * 64);
      aR1 = *(const float4*)(paBase + ls * 64 + 4);
    }
    // compute tile t
    const unsigned char* bC = smem + cur * 16384;
    const unsigned char* aC = aLDS + ((t >> 1) & 1) * 4096;
    short8 af0 = *(const short8*)(aC + aoff[0][t & 1]);
    short8 af1 = *(const short8*)(aC + aoff[1][t & 1]);
    __builtin_amdgcn_s_setprio(1);
#pragma unroll
    for (int ni = 0; ni < 4; ++ni) {
      short8 bf = *(const short8*)(bC + boffs[ni]);
      acc[0][ni] = __builtin_amdgcn_mfma_f32_16x16x32_bf16(af0, bf, acc[0][ni], 0, 0, 0);
      acc[1][ni] = __builtin_amdgcn_mfma_f32_16x16x32_bf16(af1, bf, acc[1][ni], 0, 0, 0);
    }
    __builtin_amdgcn_s_setprio(0);
    if (t == 2 || t == 4) {
      asm volatile("s_waitcnt vmcnt(2) lgkmcnt(0)" ::: "memory");  // keep aR in flight
    } else {
      asm volatile("s_waitcnt vmcnt(0) lgkmcnt(0)" ::: "memory");
    }
    __builtin_amdgcn_sched_barrier(0);
    __builtin_amdgcn_s_barrier();
  }
#undef GLLB

  // ---- epilogue overlay in dead B region ----
  float (*red)[4] = (float (*)[4])smem;              // [32][4]  (512 B)
  float* pbuf     = (float*)(smem + 512);            // [32]
  float4* pr      = (float4*)(smem + 1024);          // [256]    (4 KB)

  float pv2[4], vvf[4];
#pragma unroll
  for (int ni = 0; ni < 4; ++ni) {
    int u = wid * 64 + ni * 16 + il;
    pv2[ni] = 2.f * posb[b * UU + u];
    vvf[ni] = V[u];
  }

  float part_r[2][4];
#pragma unroll
  for (int mi = 0; mi < 2; ++mi)
#pragma unroll
    for (int r = 0; r < 4; ++r) part_r[mi][r] = 0.f;

#pragma unroll
  for (int ni = 0; ni < 4; ++ni) {
    float p2 = pv2[ni], vv = vvf[ni];
#pragma unroll
    for (int mi = 0; mi < 2; ++mi)
#pragma unroll
      for (int r = 0; r < 4; ++r) {
        float x2 = fmaf(acc[mi][ni][r], 2.f, p2);
        float e = __expf(x2);
        float tnh = __fdividef(e - 1.f, e + 1.f);
        part_r[mi][r] = fmaf(tnh, vv, part_r[mi][r]);
      }
  }
#pragma unroll
  for (int mi = 0; mi < 2; ++mi)
#pragma unroll
    for (int r = 0; r < 4; ++r) part_r[mi][r] = row16_sum(part_r[mi][r]);
  if (il == 0) {
#pragma unroll
    for (int mi = 0; mi < 2; ++mi)
#pragma unroll
      for (int r = 0; r < 4; ++r)
        red[mi * 16 + kg * 4 + r][wid] = part_r[mi][r];
  }
  __syncthreads();

  // scores + unnormalized exp (fixed reference m=0; |score| <= ||V||_1+|bv|)
  const float bvv = bvp[0];
  if (tid < 32) {
    float4 r0 = *(const float4*)red[tid];
    float sv = r0.x + r0.y + r0.z + r0.w + bvv;
    scores[(size_t)b * SS + s0 + tid] = sv;
    pbuf[tid] = __expf(sv);
  }
  __syncthreads();

  // partial context: fp32 re-read (L2-hot), unnormalized
  {
    int rg = tid >> 6;
    int d4 = (tid & 63) << 2;
    float a0 = 0.f, a1 = 0.f, a2 = 0.f, a3 = 0.f;
#pragma unroll
    for (int i = 0; i < 8; ++i) {
      int s = i * 4 + rg;
      const float4 o = *(const float4*)(optb + (size_t)s * DD + d4);
      float w = pbuf[s];
      a0 = fmaf(w, o.x, a0); a1 = fmaf(w, o.y, a1);
      a2 = fmaf(w, o.z, a2); a3 = fmaf(w, o.w, a3);
    }
    pr[tid] = make_float4(a0, a1, a2, a3);
  }
  __syncthreads();
  if (tid < 64) {
    float4 o = pr[tid];
#pragma unroll
    for (int g = 1; g < 4; ++g) {
      float4 v = pr[g * 64 + tid];
      o.x += v.x; o.y += v.y; o.z += v.z; o.w += v.w;
    }
    *(float4*)&part[(((size_t)b * NCH + ch) * DD) + (tid << 2)] = o;
  }
}

// K3: per batch — gs from scores, emit context + weights
__global__ __launch_bounds__(256) void k_final(
    const float* __restrict__ scores, const float* __restrict__ part,
    float* __restrict__ ctx, float* __restrict__ wgt) {
  __shared__ float sred[4];
  int b = blockIdx.x, t = threadIdx.x;
  int lane = t & 63, wv = t >> 6;
  const float* sb = scores + (size_t)b * SS;
  float e[16];
  float psum = 0.f;
#pragma unroll
  for (int i = 0; i < 16; ++i) {
    e[i] = __expf(sb[i * 256 + t]);
    psum += e[i];
  }
#pragma unroll
  for (int off = 32; off >= 1; off >>= 1) psum += __shfl_xor(psum, off);
  if (lane == 0) sred[wv] = psum;
  __syncthreads();
  float gs = sred[0] + sred[1] + sred[2] + sred[3];
  float inv = 1.f / gs;
  float* wb = wgt + (size_t)b * SS;
#pragma unroll
  for (int i = 0; i < 16; ++i) wb[i * 256 + t] = e[i] * inv;
  float acc = 0.f;
#pragma unroll 4
  for (int i = 0; i < NCH; ++i)
    acc += part[((size_t)b * NCH + i) * DD + t];
  ctx[b * DD + t] = acc * inv;
}

extern "C" void kernel_launch(void* const* d_in, const int* in_sizes, int n_in,
                              void* d_out, int out_size, void* d_ws, size_t ws_size,
                              hipStream_t stream) {
  const float* position = (const float*)d_in[0];
  const float* options  = (const float*)d_in[1];
  const float* W1 = (const float*)d_in[2];
  const float* b1 = (const float*)d_in[3];
  const float* W2 = (const float*)d_in[4];
  const float* b2 = (const float*)d_in[5];
  const float* V  = (const float*)d_in[6];
  const float* bv = (const float*)d_in[7];

  float* out = (float*)d_out;
  float* ctx_out = out;              // [32,256]
  float* wgt_out = out + BB * DD;    // [32,4096]

  char* ws = (char*)d_ws;
  float* posb         = (float*)ws;                          // 32 KB
  unsigned short* w2t = (unsigned short*)(ws + 32 * 1024);   // 128 KB
  float* scores       = (float*)(ws + 160 * 1024);           // 512 KB
  float* part         = (float*)(ws + 672 * 1024);           // 4 MB

  k_posproj<<<BB, 256, 0, stream>>>(position, W1, b1, b2, posb);
  k_w2t<<<dim3(16, 16), 256, 0, stream>>>(W2, w2t);
  k_score_ctx<<<dim3(NCH, BB), 256, 0, stream>>>(options, w2t, posb, V, bv,
                                                 scores, part);
  k_final<<<BB, 256, 0, stream>>>(scores, part, ctx_out, wgt_out);
}

// Round 12
// 86.712 us; speedup vs baseline: 1.0042x; 1.0042x over previous
//
#include <hip/hip_runtime.h>
#include <hip/hip_bf16.h>
#include <cstdint>
#include <cstddef>

#define BB 32
#define SS 4096
#define DD 256
#define UU 256
#define CHR 16                 // rows per chunk
#define NCHF (SS / CHR)        // 256 chunks per batch

typedef __attribute__((ext_vector_type(8))) short short8;
typedef __attribute__((ext_vector_type(4))) float f32x4;

__device__ __forceinline__ unsigned short f2bf(float x) {
  union { float f; unsigned int u; } c; c.f = x;
  unsigned int r = c.u + 0x7FFFu + ((c.u >> 16) & 1u);
  return (unsigned short)(r >> 16);
}

__device__ __forceinline__ unsigned int bfpack2(float lo, float hi) {
  union { float f; unsigned int u; } a, b;
  a.f = hi; b.f = lo;
  return __builtin_amdgcn_perm(a.u + 0x8000u, b.u + 0x8000u, 0x07060302u);
}

__device__ __forceinline__ short8 bfpack8(float4 f0, float4 f1) {
  union { unsigned int u[4]; short8 s; } r;
  r.u[0] = bfpack2(f0.x, f0.y);
  r.u[1] = bfpack2(f0.z, f0.w);
  r.u[2] = bfpack2(f1.x, f1.y);
  r.u[3] = bfpack2(f1.z, f1.w);
  return r.s;
}

// DPP row-rotate add: reduce within a 16-lane row at VALU rate
template <int CTRL>
__device__ __forceinline__ float dppadd(float x) {
  union { float f; int i; } a, b;
  a.f = x;
  b.i = __builtin_amdgcn_update_dpp(0, a.i, CTRL, 0xF, 0xF, true);
  return x + b.f;
}
__device__ __forceinline__ float row16_sum(float x) {
  x = dppadd<0x128>(x);   // row_ror:8
  x = dppadd<0x124>(x);   // row_ror:4
  x = dppadd<0x122>(x);   // row_ror:2
  x = dppadd<0x121>(x);   // row_ror:1
  return x;
}

// K1: posb[b][u] = position[b] @ W1[:,u] + b1[u] + b2[u]   (exact fp32)
__global__ void k_posproj(const float* __restrict__ pos, const float* __restrict__ W1,
                          const float* __restrict__ b1, const float* __restrict__ b2,
                          float* __restrict__ posb) {
  __shared__ float p[DD];
  int b = blockIdx.x, u = threadIdx.x;
  p[u] = pos[b * DD + u];
  __syncthreads();
  float acc = b1[u] + b2[u];
#pragma unroll 4
  for (int d = 0; d < DD; ++d) acc = fmaf(p[d], W1[(size_t)d * UU + u], acc);
  posb[b * UU + u] = acc;
}

// K1b: w2t[u][d] = bf16(W2[d][u])  (tiled transpose)
__global__ void k_w2t(const float* __restrict__ W2, unsigned short* __restrict__ w2t) {
  __shared__ unsigned short tile[16][17];
  int di = blockIdx.x * 16, ui = blockIdx.y * 16;
  int t = threadIdx.x;
  int r = t >> 4, c = t & 15;
  tile[c][r] = f2bf(W2[(size_t)(di + r) * UU + ui + c]);
  __syncthreads();
  w2t[(size_t)(ui + r) * DD + di + c] = tile[r][c];
}

// K2: wave-autonomous kernel. Grid = 256 blocks x 512 thr (1 block/CU).
// LDS: full W2^T [256u][256k] bf16, swizzled: 16B-octet o of row u stored at
//      phys = o ^ (u&7)  (bijective low bits -> 2-way-free b128 reads).
//      + per-wave 64B p-scratch @ 131072.
// ONE barrier (after W2 stage); afterwards each wave processes 4 chunks of 16
// rows fully independently: A global->reg, MFMA vs LDS-B, tanh/V epilogue,
// fixed-ref exp, ctx partial from L2-hot fp32 re-read.
__global__ __launch_bounds__(512, 2) void k_score_ctx(
    const float* __restrict__ options, const unsigned short* __restrict__ w2t,
    const float* __restrict__ posb, const float* __restrict__ V,
    const float* __restrict__ bvp, float* __restrict__ scores,
    float* __restrict__ part) {
  __shared__ __align__(16) unsigned char smem[131072 + 512];

  const int tid = threadIdx.x;
  const int wv = tid >> 6, l = tid & 63;
  const int il = l & 15, kg = l >> 4;

  // ---- one-time: stage full W2^T into LDS (gll, pre-swizzled source) ----
#pragma unroll
  for (int i = 0; i < 16; ++i) {
    int p = i * 512 + tid;            // phys 16B slot
    int u = p >> 5;
    int o = (p & 31) ^ (u & 7);       // logical octet
    __builtin_amdgcn_global_load_lds(
        (const __attribute__((address_space(1))) void*)(w2t + (size_t)u * DD + o * 8),
        (__attribute__((address_space(3))) void*)(smem + i * 8192 + wv * 1024),
        16, 0, 0);
  }
  asm volatile("s_waitcnt vmcnt(0)" ::: "memory");
  __syncthreads();                    // the ONLY block barrier

  const int g = blockIdx.x * 8 + wv;  // global wave id 0..2047
  const int b = g >> 6;               // 64 waves per batch
  const int ch0 = (g & 63) * 4;       // 4 chunks per wave

  // hoisted per-lane fragments (same b for all 4 chunks)
  float pv2[16], vvf[16];
#pragma unroll
  for (int ui = 0; ui < 16; ++ui) {
    int u = ui * 16 + il;
    pv2[ui] = 2.f * posb[b * UU + u];
    vvf[ui] = V[u];
  }
  const float bvv = bvp[0];
  float* wscr = (float*)(smem + 131072 + wv * 64);

  const int xorl = (il & 7) << 4;     // lane swizzle, byte form
  const int ubase = il * 512;

  const float* aBase =
      options + ((size_t)b * SS + (size_t)ch0 * CHR + il) * DD + kg * 8;

  // prologue: chunk 0 A burst (16 float4 in flight)
  float4 aR[16];
#pragma unroll
  for (int t = 0; t < 8; ++t) {
    aR[2 * t]     = *(const float4*)(aBase + t * 32);
    aR[2 * t + 1] = *(const float4*)(aBase + t * 32 + 4);
  }

  for (int j = 0; j < 4; ++j) {
    const int ch = ch0 + j;

    // pack current A to bf16 fragments
    short8 af[8];
#pragma unroll
    for (int t = 0; t < 8; ++t) af[t] = bfpack8(aR[2 * t], aR[2 * t + 1]);

    // prefetch next chunk's A (T14: overlaps this chunk's MFMA/epilogue)
    if (j < 3) {
      const float* nb = aBase + (size_t)(j + 1) * CHR * DD;
#pragma unroll
      for (int t = 0; t < 8; ++t) {
        aR[2 * t]     = *(const float4*)(nb + t * 32);
        aR[2 * t + 1] = *(const float4*)(nb + t * 32 + 4);
      }
    }

    // K-loop: 8 ksteps x 16 u-tiles, B from LDS (swizzled), zero barriers
    f32x4 acc[16];
#pragma unroll
    for (int ui = 0; ui < 16; ++ui) {
      f32x4 z = {0.f, 0.f, 0.f, 0.f};
      acc[ui] = z;
    }
#pragma unroll
    for (int t = 0; t < 8; ++t) {
#pragma unroll
      for (int ui = 0; ui < 16; ++ui) {
        short8 bf = *(const short8*)(
            smem + ui * 8192 + ubase + ((((4 * t + kg) << 4)) ^ xorl));
        acc[ui] = __builtin_amdgcn_mfma_f32_16x16x32_bf16(af[t], bf, acc[ui], 0, 0, 0);
      }
    }

    // epilogue: tanh(acc + posb) * V, per-lane over (ui, r)
    float part_r[4] = {0.f, 0.f, 0.f, 0.f};
#pragma unroll
    for (int ui = 0; ui < 16; ++ui) {
      float p2 = pv2[ui], vv = vvf[ui];
#pragma unroll
      for (int r = 0; r < 4; ++r) {
        float x2 = fmaf(acc[ui][r], 2.f, p2);
        float e = __expf(x2);
        float rc = __frcp_rn(e + 1.f);
        float tnh = fmaf(-2.f, rc, 1.f);
        part_r[r] = fmaf(tnh, vv, part_r[r]);
      }
    }
#pragma unroll
    for (int r = 0; r < 4; ++r) part_r[r] = row16_sum(part_r[r]);

    // rows kg*4+r complete in lanes il==0; scores + exp (fixed ref m=0)
    if (il == 0) {
#pragma unroll
      for (int r = 0; r < 4; ++r) {
        float sv = part_r[r] + bvv;
        scores[(size_t)b * SS + (size_t)ch * CHR + kg * 4 + r] = sv;
        wscr[kg * 4 + r] = __expf(sv);
      }
    }
    asm volatile("s_waitcnt lgkmcnt(0)" ::: "memory");
    __builtin_amdgcn_sched_barrier(0);

    // ctx partial: fp32 re-read (L2-hot), weighted by wscr broadcast
    {
      const float* rowp =
          options + ((size_t)b * SS + (size_t)ch * CHR) * DD + l * 4;
      float c0 = 0.f, c1 = 0.f, c2 = 0.f, c3 = 0.f;
#pragma unroll
      for (int s = 0; s < 16; ++s) {
        float w = wscr[s];
        float4 o = *(const float4*)(rowp + (size_t)s * DD);
        c0 = fmaf(w, o.x, c0); c1 = fmaf(w, o.y, c1);
        c2 = fmaf(w, o.z, c2); c3 = fmaf(w, o.w, c3);
      }
      float4 o4 = make_float4(c0, c1, c2, c3);
      *(float4*)&part[((size_t)b * NCHF + ch) * DD + l * 4] = o4;
    }
  }
}

// K3: per batch — gs from scores, emit context + weights
__global__ __launch_bounds__(256) void k_final(
    const float* __restrict__ scores, const float* __restrict__ part,
    float* __restrict__ ctx, float* __restrict__ wgt) {
  __shared__ float sred[4];
  int b = blockIdx.x, t = threadIdx.x;
  int lane = t & 63, wvv = t >> 6;
  const float* sb = scores + (size_t)b * SS;
  float e[16];
  float psum = 0.f;
#pragma unroll
  for (int i = 0; i < 16; ++i) {
    e[i] = __expf(sb[i * 256 + t]);
    psum += e[i];
  }
#pragma unroll
  for (int off = 32; off >= 1; off >>= 1) psum += __shfl_xor(psum, off);
  if (lane == 0) sred[wvv] = psum;
  __syncthreads();
  float gs = sred[0] + sred[1] + sred[2] + sred[3];
  float inv = 1.f / gs;
  float* wb = wgt + (size_t)b * SS;
#pragma unroll
  for (int i = 0; i < 16; ++i) wb[i * 256 + t] = e[i] * inv;
  float acc = 0.f;
#pragma unroll 8
  for (int i = 0; i < NCHF; ++i)
    acc += part[((size_t)b * NCHF + i) * DD + t];
  ctx[b * DD + t] = acc * inv;
}

extern "C" void kernel_launch(void* const* d_in, const int* in_sizes, int n_in,
                              void* d_out, int out_size, void* d_ws, size_t ws_size,
                              hipStream_t stream) {
  const float* position = (const float*)d_in[0];
  const float* options  = (const float*)d_in[1];
  const float* W1 = (const float*)d_in[2];
  const float* b1 = (const float*)d_in[3];
  const float* W2 = (const float*)d_in[4];
  const float* b2 = (const float*)d_in[5];
  const float* V  = (const float*)d_in[6];
  const float* bv = (const float*)d_in[7];

  float* out = (float*)d_out;
  float* ctx_out = out;              // [32,256]
  float* wgt_out = out + BB * DD;    // [32,4096]

  char* ws = (char*)d_ws;
  float* posb         = (float*)ws;                          // 32 KB
  unsigned short* w2t = (unsigned short*)(ws + 32 * 1024);   // 128 KB
  float* scores       = (float*)(ws + 160 * 1024);           // 512 KB
  float* part         = (float*)(ws + 672 * 1024);           // 8 MB

  k_posproj<<<BB, 256, 0, stream>>>(position, W1, b1, b2, posb);
  k_w2t<<<dim3(16, 16), 256, 0, stream>>>(W2, w2t);
  k_score_ctx<<<256, 512, 0, stream>>>(options, w2t, posb, V, bv, scores, part);
  k_final<<<BB, 256, 0, stream>>>(scores, part, ctx_out, wgt_out);
}